// Round 1
// baseline (614.219 us; speedup 1.0000x reference)
//
#include <hip/hip_runtime.h>
#include <math.h>

// Problem constants (fixed by setup_inputs)
#define B 8
#define R 4096
#define C 1024
#define NROWS (B * R)            // 32768
#define F4_PER_ROW (C / 4)       // 256
#define BLOCKS_PER_BATCH 1024    // k_mags_select: 4 rows/block, 4096 rows/batch

// Native clang vector type — accepted by __builtin_nontemporal_store.
typedef float vfloat4 __attribute__((ext_vector_type(4)));

// ---------------------------------------------------------------------------
// Kernel 0: per-batch init. Zeroes the completion counters (workspace is
// poisoned each iteration, so this must run every launch) and computes
// rows_to_keep[b] from the score head (doesn't depend on mags, so it moves
// off the select critical path). 8 blocks x 128 threads, ~1-2 us.
// ---------------------------------------------------------------------------
__global__ void k_init(const float* __restrict__ logits,
                       const float* __restrict__ sw,
                       const float* __restrict__ sb,
                       unsigned* __restrict__ cnt,
                       int* __restrict__ kkeep) {
    const int b = blockIdx.x, t = threadIdx.x;   // 128 threads
    if (t == 0) cnt[b] = 0u;
    double a = 0.0;
#pragma unroll
    for (int j = 0; j < 8; ++j) {
        const int idx = t + j * 128;
        a += (double)logits[b * C + idx] * (double)sw[idx];
    }
    for (int off = 32; off > 0; off >>= 1)
        a += __shfl_down(a, off, 64);
    __shared__ double dred[2];
    if ((t & 63) == 0) dred[t >> 6] = a;
    __syncthreads();
    if (t == 0) {
        double s = (double)sb[0] + dred[0] + dred[1];
        double kf = 1.0 / (1.0 + exp(-s));
        int k = (int)(kf * (double)R);   // truncation, kf >= 0 (matches ref astype)
        if (k < 1) k = 1;
        if (k > R) k = R;
        kkeep[b] = k;
    }
}

// ---------------------------------------------------------------------------
// Kernel 1: row magnitudes + FUSED radix select via last-block-done.
// One wave per row, 4 waves/block -> 8192 blocks. float4 loads, double acc
// (ordering fidelity near the k-th order statistic; passes absmax=0.0).
// The last block to finish a batch (device-scope counter) runs the exact
// 4-pass radix select for that batch with its 256 threads, overlapped with
// the remaining mags blocks — this removes the previously serialized
// 8-block k_select dispatch from the critical path.
// Coherence: release = __syncthreads (drains stores, vmcnt(0)) +
// __threadfence (agent-scope: L2 writeback) before atomicAdd; acquire =
// __threadfence (cache invalidate) after observing the final count.
// Handles cross-XCD L2 non-coherence per the gfx942+ fence mapping.
// ---------------------------------------------------------------------------
__global__ void k_mags_select(const float* __restrict__ wp,
                              float* __restrict__ mags,
                              unsigned* __restrict__ cnt,
                              const int* __restrict__ kkeep,
                              float* __restrict__ thr) {
    __shared__ unsigned s_old;
    __shared__ unsigned hist[256];
    __shared__ unsigned sh_prefix;
    __shared__ int sh_krem;

    const int t    = threadIdx.x;
    const int row  = blockIdx.x * 4 + (t >> 6);
    const int lane = t & 63;
    const int b    = blockIdx.x >> 10;           // BLOCKS_PER_BATCH = 1024

    // ---- phase 1: this block's 4 row norms --------------------------------
    const vfloat4* p = (const vfloat4*)(wp + (size_t)row * C);
    double acc = 0.0;
#pragma unroll
    for (int j = 0; j < 4; ++j) {
        vfloat4 v = p[j * 64 + lane];
        acc += (double)v.x * v.x + (double)v.y * v.y +
               (double)v.z * v.z + (double)v.w * v.w;
    }
    for (int off = 32; off > 0; off >>= 1)
        acc += __shfl_down(acc, off, 64);
    if (lane == 0) mags[row] = (float)sqrt(acc);

    // ---- last-block-done detection (no spin: deadlock-free) ---------------
    __syncthreads();                  // all 4 waves' stores drained (vmcnt(0))
    if (t == 0) {
        __threadfence();              // release: write back dirty L2 lines
        s_old = atomicAdd(&cnt[b], 1u);
    }
    __syncthreads();
    if (s_old != BLOCKS_PER_BATCH - 1u) return;

    // ---- we are the last block of batch b: exact radix select -------------
    __threadfence();                  // acquire: invalidate L1/L2 for fresh mags

    unsigned u[16];                   // 4096 norms, 16 per thread
#pragma unroll
    for (int j = 0; j < 16; ++j)
        u[j] = __float_as_uint(mags[b * R + t + j * 256]);

    if (t == 0) {
        sh_prefix = 0u;
        sh_krem   = kkeep[b];
    }

    const int shifts[4] = {24, 16, 8, 0};
    const unsigned maskH[4] = {0x00000000u, 0xFF000000u, 0xFFFF0000u, 0xFFFFFF00u};
#pragma unroll
    for (int p4 = 0; p4 < 4; ++p4) {
        const int shift = shifts[p4];
        const unsigned mh = maskH[p4];
        hist[t] = 0u;
        __syncthreads();              // also publishes sh_prefix/sh_krem (p4==0)
        const unsigned pref = sh_prefix;
        const int krem = sh_krem;
#pragma unroll
        for (int j = 0; j < 16; ++j) {
            if ((u[j] & mh) == pref)
                atomicAdd(&hist[(u[j] >> shift) & 255u], 1u);
        }
        __syncthreads();
        if (t < 64) {  // wave 0: suffix scan over 256 bins, 4 bins/lane
            unsigned h0 = hist[4 * t], h1 = hist[4 * t + 1],
                     h2 = hist[4 * t + 2], h3 = hist[4 * t + 3];
            unsigned s4 = h0 + h1 + h2 + h3;
            unsigned suf = s4;
            for (int off = 1; off < 64; off <<= 1) {
                unsigned tmp = __shfl_down(suf, off, 64);
                if ((t & 63) + off < 64) suf += tmp;
            }
            unsigned below = suf - s4;  // count in bins strictly above this group
            if ((int)suf >= krem && (int)below < krem) {
                unsigned hh[4] = {h0, h1, h2, h3};
                unsigned cum = below;
                for (int bb = 3; bb >= 0; --bb) {
                    cum += hh[bb];
                    if ((int)cum >= krem) {
                        sh_krem   = krem - (int)(cum - hh[bb]);
                        sh_prefix = pref | ((unsigned)(4 * t + bb) << shift);
                        break;
                    }
                }
            }
        }
        __syncthreads();
    }
    if (t == 0) thr[b] = __uint_as_float(sh_prefix);
}

// ---------------------------------------------------------------------------
// Kernel 2: out = wp * (mags[row] >= thr[batch]).
// 8 rows/block (4096 blocks x 256 threads), one float4/thread/row.
// Masked rows write zeros WITHOUT reading wp. Branch is block-uniform.
// Kept-row reads largely hit Infinity Cache (wp < 256 MiB, just streamed).
// ---------------------------------------------------------------------------
__global__ void k_apply(const float* __restrict__ wp,
                        const float* __restrict__ mags,
                        const float* __restrict__ thr,
                        float* __restrict__ out) {
    const int t = threadIdx.x;
    const int row0 = blockIdx.x * 8;           // 8 rows per block
    const int b = row0 >> 12;                  // all 8 rows in same batch
    const float tb = thr[b];
    const vfloat4* src = ((const vfloat4*)wp) + (size_t)row0 * F4_PER_ROW;
    vfloat4*       dst = ((vfloat4*)out)      + (size_t)row0 * F4_PER_ROW;
#pragma unroll
    for (int j = 0; j < 8; ++j) {
        if (mags[row0 + j] >= tb) {
            vfloat4 v = src[j * F4_PER_ROW + t];
            __builtin_nontemporal_store(v, &dst[j * F4_PER_ROW + t]);
        } else {
            vfloat4 z = {0.0f, 0.0f, 0.0f, 0.0f};
            __builtin_nontemporal_store(z, &dst[j * F4_PER_ROW + t]);
        }
    }
}

extern "C" void kernel_launch(void* const* d_in, const int* in_sizes, int n_in,
                              void* d_out, int out_size, void* d_ws, size_t ws_size,
                              hipStream_t stream) {
    const float* wp     = (const float*)d_in[0];  // [8,4096,1024]
    const float* logits = (const float*)d_in[1];  // [8,1024]
    const float* sw     = (const float*)d_in[2];  // [1024,1]
    const float* sb     = (const float*)d_in[3];  // [1]
    float* out = (float*)d_out;

    // Workspace: mags (32768 f32) | thr (8 f32) | cnt (8 u32) | kkeep (8 i32)
    float*    mags  = (float*)d_ws;
    float*    thr   = mags + NROWS;
    unsigned* cnt   = (unsigned*)(thr + B);
    int*      kkeep = (int*)(cnt + B);

    k_init       <<<B, 128, 0, stream>>>(logits, sw, sb, cnt, kkeep);
    k_mags_select<<<NROWS / 4, 256, 0, stream>>>(wp, mags, cnt, kkeep, thr);
    k_apply      <<<NROWS / 8, 256, 0, stream>>>(wp, mags, thr, out);
}

// Round 3
// 244.762 us; speedup vs baseline: 2.5095x; 2.5095x over previous
//
#include <hip/hip_runtime.h>
#include <math.h>

// Problem constants (fixed by setup_inputs)
#define B 8
#define R 4096
#define C 1024
#define NROWS (B * R)          // 32768
#define F4_PER_ROW (C / 4)     // 256

// Native clang vector type — accepted by __builtin_nontemporal_store
// (HIP's float4 is a struct and is rejected).
typedef float vfloat4 __attribute__((ext_vector_type(4)));

// ---------------------------------------------------------------------------
// Kernel 1: row_magnitudes[row] = ||weight_params[row, :]||_2
// One wave per row, 4 waves/block -> 8192 blocks. float4 loads, double acc
// (ordering fidelity near the k-th order statistic; passes absmax=0.0).
// R1 lesson: NO fences, NO global atomics here — agent-scope fences emit
// buffer_wbl2/inv per block on gfx950 (non-coherent per-XCD L2) and
// serialized the TCC pipeline into a 432 us disaster.
// Two independent accumulators halve the 32-deep f64 FMA chain.
// ---------------------------------------------------------------------------
__global__ void k_mags(const float* __restrict__ wp,
                       float* __restrict__ mags) {
    int row  = blockIdx.x * 4 + (threadIdx.x >> 6);
    int lane = threadIdx.x & 63;
    const vfloat4* p = (const vfloat4*)(wp + (size_t)row * C);
    double acc0 = 0.0, acc1 = 0.0;
#pragma unroll
    for (int j = 0; j < 4; j += 2) {
        vfloat4 v = p[j * 64 + lane];
        vfloat4 w = p[(j + 1) * 64 + lane];
        acc0 += (double)v.x * v.x + (double)v.y * v.y +
                (double)v.z * v.z + (double)v.w * v.w;
        acc1 += (double)w.x * w.x + (double)w.y * w.y +
                (double)w.z * w.z + (double)w.w * w.w;
    }
    double acc = acc0 + acc1;
    for (int off = 32; off > 0; off >>= 1)
        acc += __shfl_down(acc, off, 64);
    if (lane == 0) mags[row] = (float)sqrt(acc);
}

// ---------------------------------------------------------------------------
// Kernel 2: per batch (8 blocks x 256 threads): fused score + 4-pass radix
// select (exact k-th largest row norm via u32 bit-pattern monotonicity).
// R2 change: 256 threads (was 1024) — the ~13 __syncthreads() in the radix
// passes cost ~4x less on a 4-wave block than a 16-wave block; LDS-atomic
// histogram work is identical (16 values/thread instead of 4).
// ---------------------------------------------------------------------------
__global__ void k_select(const float* __restrict__ logits,
                         const float* __restrict__ sw,
                         const float* __restrict__ sb,
                         const float* __restrict__ mags,
                         float* __restrict__ thr) {
    __shared__ unsigned hist[256];
    __shared__ double dred[4];
    __shared__ unsigned sh_prefix;
    __shared__ int sh_krem;

    const int b = blockIdx.x, t = threadIdx.x;   // 256 threads
    const int lane = t & 63;

    // ---- Phase 0: rows_to_keep (score head) ------------------------------
    double a = 0.0;
#pragma unroll
    for (int j = 0; j < 4; ++j) {
        const int idx = t + j * 256;
        a += (double)logits[b * C + idx] * (double)sw[idx];
    }
    for (int off = 32; off > 0; off >>= 1)
        a += __shfl_down(a, off, 64);
    if (lane == 0) dred[t >> 6] = a;

    // ---- load this batch's norms into registers as sortable u32 ----------
    unsigned u[16];
#pragma unroll
    for (int j = 0; j < 16; ++j)
        u[j] = __float_as_uint(mags[b * R + t + j * 256]);

    __syncthreads();
    if (t == 0) {
        double s = (double)sb[0] + dred[0] + dred[1] + dred[2] + dred[3];
        double kf = 1.0 / (1.0 + exp(-s));
        int k = (int)(kf * (double)R);   // truncation, kf >= 0 (matches astype)
        if (k < 1) k = 1;
        if (k > R) k = R;
        sh_krem = k;
        sh_prefix = 0u;
    }

    // ---- Phase 1-4: radix select, high byte -> low byte -------------------
    const int shifts[4] = {24, 16, 8, 0};
    const unsigned maskH[4] = {0x00000000u, 0xFF000000u, 0xFFFF0000u, 0xFFFFFF00u};
#pragma unroll
    for (int p4 = 0; p4 < 4; ++p4) {
        const int shift = shifts[p4];
        const unsigned mh = maskH[p4];
        hist[t] = 0u;
        __syncthreads();              // also publishes sh_prefix/sh_krem (p4==0)
        const unsigned pref = sh_prefix;
        const int krem = sh_krem;
#pragma unroll
        for (int j = 0; j < 16; ++j) {
            if ((u[j] & mh) == pref)
                atomicAdd(&hist[(u[j] >> shift) & 255u], 1u);
        }
        __syncthreads();
        if (t < 64) {  // wave 0: suffix scan over 256 bins, 4 bins/lane
            unsigned h0 = hist[4 * t], h1 = hist[4 * t + 1],
                     h2 = hist[4 * t + 2], h3 = hist[4 * t + 3];
            unsigned s4 = h0 + h1 + h2 + h3;
            unsigned suf = s4;
            for (int off = 1; off < 64; off <<= 1) {
                unsigned tmp = __shfl_down(suf, off, 64);
                if (lane + off < 64) suf += tmp;
            }
            unsigned below = suf - s4;  // count in bins strictly above this group
            if ((int)suf >= krem && (int)below < krem) {
                unsigned hh[4] = {h0, h1, h2, h3};
                unsigned cum = below;
                for (int bb = 3; bb >= 0; --bb) {
                    cum += hh[bb];
                    if ((int)cum >= krem) {
                        sh_krem   = krem - (int)(cum - hh[bb]);
                        sh_prefix = pref | ((unsigned)(4 * t + bb) << shift);
                        break;
                    }
                }
            }
        }
        __syncthreads();
    }
    if (t == 0) thr[b] = __uint_as_float(sh_prefix);
}

// ---------------------------------------------------------------------------
// Kernel 3: out = wp * (mags[row] >= thr[batch]).
// 8 rows/block (4096 blocks x 256 threads), one float4/thread/row.
// Masked rows write zeros WITHOUT reading wp (only remaining traffic cut).
// Branch is block-uniform (mask depends only on row), so no divergence.
// Nontemporal stores keep out from thrashing L3, preserving wp residency
// for the kept-row re-reads.
// ---------------------------------------------------------------------------
__global__ void k_apply(const float* __restrict__ wp,
                        const float* __restrict__ mags,
                        const float* __restrict__ thr,
                        float* __restrict__ out) {
    const int t = threadIdx.x;
    const int row0 = blockIdx.x * 8;           // 8 rows per block
    const int b = row0 >> 12;                  // all 8 rows in same batch
    const float tb = thr[b];
    // hoist the 8 row masks (block-uniform) ahead of the copy loop
    bool keep[8];
#pragma unroll
    for (int j = 0; j < 8; ++j) keep[j] = (mags[row0 + j] >= tb);
    const vfloat4* src = ((const vfloat4*)wp) + (size_t)row0 * F4_PER_ROW;
    vfloat4*       dst = ((vfloat4*)out)      + (size_t)row0 * F4_PER_ROW;
#pragma unroll
    for (int j = 0; j < 8; ++j) {
        if (keep[j]) {
            vfloat4 v = src[j * F4_PER_ROW + t];
            __builtin_nontemporal_store(v, &dst[j * F4_PER_ROW + t]);
        } else {
            vfloat4 z = {0.0f, 0.0f, 0.0f, 0.0f};
            __builtin_nontemporal_store(z, &dst[j * F4_PER_ROW + t]);
        }
    }
}

extern "C" void kernel_launch(void* const* d_in, const int* in_sizes, int n_in,
                              void* d_out, int out_size, void* d_ws, size_t ws_size,
                              hipStream_t stream) {
    const float* wp     = (const float*)d_in[0];  // [8,4096,1024]
    const float* logits = (const float*)d_in[1];  // [8,1024]
    const float* sw     = (const float*)d_in[2];  // [1024,1]
    const float* sb     = (const float*)d_in[3];  // [1]
    float* out = (float*)d_out;

    // Workspace: mags (32768 f32 = 128 KiB) | thr (8 f32)
    float* mags = (float*)d_ws;
    float* thr  = mags + NROWS;

    k_mags  <<<NROWS / 4, 256, 0, stream>>>(wp, mags);
    k_select<<<B, 256, 0, stream>>>(logits, sw, sb, mags, thr);
    k_apply <<<NROWS / 8, 256, 0, stream>>>(wp, mags, thr, out);
}